// Round 5
// baseline (165.226 us; speedup 1.0000x reference)
//
#include <hip/hip_runtime.h>

// Problem constants (from reference)
#define BATCH 16
#define NENT  512
#define D_IN  256
#define D_OUT 32
#define CSP   64
#define COUT  96        // 64 spatial + 32 scatter channels
#define HWDIM 256
#define HWSZ  65536     // 256*256
#define HW4   16384     // HWSZ/4  (2^14)
#define SP_B4  (CSP * HW4)    // 2^20 float4: spatial part per batch
#define SC_B4  (D_OUT * HW4)  // 2^19 float4: scatter part per batch
#define OUT_B4 (COUT * HW4)   // float4 per batch in out

// K_Z: pure-store fill. Zeros the scatter region of out (16 x 2^19 float4)
// and the owner array (4 MB). Grid-stride, all index math shifts/masks.
__global__ void zero_kernel(float4* __restrict__ out,
                            int4* __restrict__ owner4) {
    const int SC_TOT = BATCH * SC_B4;          // 8,388,608 float4
    const int OW4    = BATCH * HWSZ / 4;       // 262,144 int4
    const int total  = SC_TOT + OW4;
    const int stride = gridDim.x * blockDim.x; // 524,288
    const float4 z4 = make_float4(0.f, 0.f, 0.f, 0.f);
    for (int i = blockIdx.x * blockDim.x + threadIdx.x; i < total; i += stride) {
        if (i < SC_TOT) {
            int b = i >> 19;
            int r = i & (SC_B4 - 1);
            out[(size_t)b * OUT_B4 + SP_B4 + r] = z4;
        } else {
            owner4[i - SC_TOT] = make_int4(0, 0, 0, 0);
        }
    }
}

// K_B: last-write-wins resolution. owner[b, flat] = max(n+1).
__global__ void owner_kernel(const int* __restrict__ loc,
                             int* __restrict__ owner) {
    int gid = blockIdx.x * blockDim.x + threadIdx.x;   // 0 .. 8191
    if (gid >= BATCH * NENT) return;
    int h = loc[gid * 2 + 0];
    int w = loc[gid * 2 + 1];
    h = min(max(h, 0), HWDIM - 1);
    w = min(max(w, 0), HWDIM - 1);
    int b = gid >> 9;
    int n = gid & (NENT - 1);
    atomicMax(&owner[b * HWSZ + h * HWDIM + w], n + 1);
}

// K_C: pure float4 copy, 2 linear segments per thread. grid = (2048, BATCH).
__global__ void copy_kernel(const float4* __restrict__ sp,
                            float4* __restrict__ out) {
    const int PER = 2048 * 256;                        // 524,288
    int b = blockIdx.y;
    int t = blockIdx.x * blockDim.x + threadIdx.x;
    const float4* spb  = sp  + (size_t)b * SP_B4;
    float4*       outb = out + (size_t)b * OUT_B4;
    outb[t]       = spb[t];
    outb[t + PER] = spb[t + PER];
}

// K_S: projection + direct winner scatter. Thread = (entity, e).
// ~99.5% of entities win their pixel; each writes one dword at
// out[b, 64+e, flat]. emb row broadcasts within each 32-lane group,
// Wp column reads coalesce across e-lanes.
__global__ void proj_scatter_kernel(const float* __restrict__ emb,
                                    const float* __restrict__ Wp,
                                    const float* __restrict__ bp,
                                    const int* __restrict__ loc,
                                    const int* __restrict__ owner,
                                    float* __restrict__ out) {
    int gid = blockIdx.x * blockDim.x + threadIdx.x;   // 0 .. 262,143
    int ent = gid >> 5;          // entity index 0..8191
    int e   = gid & 31;          // output feature 0..31
    int b   = ent >> 9;
    int n   = ent & (NENT - 1);

    int h = loc[ent * 2 + 0];
    int w = loc[ent * 2 + 1];
    h = min(max(h, 0), HWDIM - 1);
    w = min(max(w, 0), HWDIM - 1);
    int flat = h * HWDIM + w;

    if (owner[b * HWSZ + flat] != n + 1) return;   // lost to a later entity

    float acc = bp[e];
    const float* er = emb + ent * D_IN;
    #pragma unroll 8
    for (int d = 0; d < D_IN; ++d) {
        acc += er[d] * Wp[d * D_OUT + e];
    }
    out[(size_t)b * (COUT * HWSZ) + (CSP + e) * HWSZ + flat] = acc;
}

extern "C" void kernel_launch(void* const* d_in, const int* in_sizes, int n_in,
                              void* d_out, int out_size, void* d_ws, size_t ws_size,
                              hipStream_t stream) {
    const float* spatial = (const float*)d_in[0];   // [16,64,256,256]
    const float* emb     = (const float*)d_in[1];   // [16,512,256]
    const float* Wp      = (const float*)d_in[2];   // [256,32]
    const float* bp      = (const float*)d_in[3];   // [32]
    const int*   loc     = (const int*)d_in[4];     // [16,512,2]
    float* out = (float*)d_out;                     // [16,96,256,256]
    int* owner = (int*)d_ws;                        // 4 MB

    // Z: pure-store zero of scatter region + owner
    zero_kernel<<<2048, 256, 0, stream>>>((float4*)out, (int4*)owner);
    // B: resolve duplicate locations (last write wins)
    owner_kernel<<<32, 256, 0, stream>>>(loc, owner);
    // C: pure float4 copy of the 64 spatial channels
    dim3 cgrid(2048, BATCH);
    copy_kernel<<<cgrid, 256, 0, stream>>>((const float4*)spatial, (float4*)out);
    // S: project + scatter winners directly into out
    proj_scatter_kernel<<<1024, 256, 0, stream>>>(emb, Wp, bp, loc, owner, out);
}